// Round 9
// baseline (119.670 us; speedup 1.0000x reference)
//
#include <hip/hip_runtime.h>
#include <hip/hip_bf16.h>

// Problem constants
#define BATCH 2
#define GRP   2
#define NBG   4            // BATCH*GRP
#define CINCH 192          // input channels
#define OG    192          // output channels per group
#define HWDIM 48
#define LPIX  2304         // 48*48
#define KTAP  25           // 5x5
#define IDIM  4800         // CINCH*KTAP
#define NCHUNK 150         // IDIM/32
#define KSPLIT 5           // one kernel row (5 taps) per split
#define XPAD  24576        // 128 l-rows * 192 c of padding each side of g_xt
#define OUTEL (NBG * OG * LPIX)   // 1769472
#define LROW  400          // LDS bytes per staged B row (384 data + 16 pad)
#define ZOFF  (132 * LROW) // zero line offset (52800)
#define AOFF  (ZOFF + 64)  // A double-buffer offset; LDS total = AOFF + 16384

typedef __attribute__((ext_vector_type(4))) float  float4v;
typedef __attribute__((ext_vector_type(8))) short  short8;

// Static device scratch
// A, fragment-major: [bg][t][ot(3)][i(4)][m(16)][q(4)][e(8)] bf16
__device__ __align__(16) unsigned short g_wa[(size_t)NBG * NCHUNK * 6144];
__device__ __align__(16) unsigned short g_xt[XPAD + BATCH * LPIX * CINCH + XPAD]; // [b][l][c] bf16, padded
__device__ unsigned long long g_m64[NBG * LPIX];   // 50 mask bits per (bg,l)

__device__ __forceinline__ unsigned short f2bf(float f) {
  union { float f; unsigned int u; } un; un.f = f;
  unsigned int u = un.u;
  return (unsigned short)((u + 0x7fffu + ((u >> 16) & 1u)) >> 16);  // RNE
}

// ---------------------------------------------------------------------------
// ONE prep dispatch, block ranges:
//  [0,216)      transpose+cvt x -> g_xt
//  [216,984)    reorder dkw -> g_wa (fragment-major, coalesced 64B stores)
//  [984,1176)   mask bits -> g_m64
//  [1176,1200)  zero g_xt pads
//  [1200,2928)  init out[row][l] = dkb[row]  (gemm atomically accumulates)
__global__ __launch_bounds__(256) void prep(
    const float* __restrict__ x, const int* __restrict__ tg,
    const float* __restrict__ dkw, const float* __restrict__ dkb,
    float* __restrict__ out) {
  __shared__ __align__(16) unsigned char smem[19200];
  const int bx = blockIdx.x, tid = threadIdx.x;

  if (bx < 216) {  // ---- transpose: 64c x 64l tiles via LDS (stride 68)
    unsigned short* tile = (unsigned short*)smem;
    const int c0 = (bx % 3) * 64;
    const int l0 = ((bx / 3) % 36) * 64;
    const int b  = bx / 108;
    #pragma unroll
    for (int it = 0; it < 4; ++it) {
      const int idx = it * 256 + tid;
      const int cl = idx >> 4, lq = idx & 15;
      const float4 v = reinterpret_cast<const float4*>(
          x + ((size_t)b * CINCH + c0 + cl) * LPIX + l0)[lq];
      unsigned short* tp = &tile[cl * 68 + lq * 4];
      tp[0] = f2bf(v.x); tp[1] = f2bf(v.y); tp[2] = f2bf(v.z); tp[3] = f2bf(v.w);
    }
    __syncthreads();
    unsigned short* dst = g_xt + XPAD + ((size_t)b * LPIX) * CINCH;
    #pragma unroll
    for (int it = 0; it < 2; ++it) {
      const int idx = it * 256 + tid;
      const int c8 = idx & 7, ll = idx >> 3;
      unsigned short pk[8];
      #pragma unroll
      for (int e = 0; e < 8; ++e) pk[e] = tile[(c8 * 8 + e) * 68 + ll];
      *reinterpret_cast<uint4*>(dst + (size_t)(l0 + ll) * CINCH + c0 + c8 * 8) =
          *reinterpret_cast<const uint4*>(pk);
    }
  } else if (bx < 984) {  // ---- weight reorder, fragment-major
    float* row = (float*)smem;                 // 4800 floats
    const int blk = bx - 216;                  // bg*192 + o
    const int bg = blk / OG, o = blk % OG;
    const float* src = dkw + (size_t)blk * IDIM;
    for (int i = tid; i < IDIM / 4; i += 256)
      reinterpret_cast<float4*>(row)[i] = reinterpret_cast<const float4*>(src)[i];
    __syncthreads();
    const int ot = o >> 6, fi = (o >> 4) & 3, m = o & 15;
    unsigned short* wbase =
        g_wa + (size_t)bg * NCHUNK * 6144 + ot * 2048 + fi * 512 + m * 32;
    for (int t = tid; t < NCHUNK; t += 256) {  // one 64B granule per t
      const int kk = t / 6, c0 = (t % 6) * 32;
      unsigned int pk[16];
      #pragma unroll
      for (int q = 0; q < 4; ++q)
        #pragma unroll
        for (int e = 0; e < 4; ++e) {
          const int c = c0 + q * 8 + e * 2;
          const unsigned lo = f2bf(row[c * KTAP + kk]);
          const unsigned hi = f2bf(row[(c + 1) * KTAP + kk]);
          pk[q * 4 + e] = lo | (hi << 16);
        }
      unsigned short* dst = wbase + (size_t)t * 6144;
      #pragma unroll
      for (int q = 0; q < 4; ++q)
        reinterpret_cast<uint4*>(dst)[q] = *reinterpret_cast<const uint4*>(pk + q * 4);
    }
  } else if (bx < 1176) {  // ---- mask bits
    const int blk = bx - 984;                  // bg*48 + h
    const int bg = blk / HWDIM, h = blk % HWDIM;
    const int b = bg >> 1, g = bg & 1;
    int* tgs = (int*)smem;                     // [2][5][48]
    for (int i = tid; i < 480; i += 256) {
      const int g2 = i / 240, r5 = (i / 48) % 5, w = i % 48;
      const int hh = h + r5 - 2;
      tgs[i] = (hh >= 0 && hh < HWDIM)
                   ? tg[((b * GRP + g2) * HWDIM + hh) * HWDIM + w]
                   : 0x7fffffff;
    }
    __syncthreads();
    if (tid < HWDIM) {
      const int w = tid;
      const int center = tgs[g * 240 + 96 + w];
      unsigned long long bits = 0ull;
      #pragma unroll
      for (int g2 = 0; g2 < GRP; ++g2)
        #pragma unroll
        for (int kk = 0; kk < KTAP; ++kk) {
          const int ww = w + kk % 5 - 2;
          if (ww >= 0 && ww < HWDIM && tgs[g2 * 240 + (kk / 5) * 48 + ww] < center)
            bits |= 1ull << (g2 * KTAP + kk);
        }
      g_m64[bg * LPIX + h * HWDIM + w] = bits;
    }
  } else if (bx < 1200) {  // ---- zero g_xt pads (2 x 48 KiB)
    const int idx = (bx - 1176) * 256 + tid;   // 0..6143, 16B each
    uint4 z; z.x = z.y = z.z = z.w = 0u;
    if (idx < 3072)
      reinterpret_cast<uint4*>(g_xt)[idx] = z;
    else
      reinterpret_cast<uint4*>(g_xt + XPAD + (size_t)BATCH * LPIX * CINCH)[idx - 3072] = z;
  } else {  // ---- init out with bias: one float4 (4 l-positions) per thread
    const int idx = (bx - 1200) * 256 + tid;   // 0..442367
    const int row = idx / (LPIX / 4);          // bg*192 + o, 0..767
    const float bias = dkb[row];
    float4 v; v.x = v.y = v.z = v.w = bias;
    reinterpret_cast<float4*>(out)[idx] = v;
  }
}

// ---------------------------------------------------------------------------
// GEMM (R20): body identical to R17 (best measured: 107.5us total) -- 256
// threads, o64 x l128 tile, wave tile o64 x l32, B window + zero line in
// LDS, A staged by 16B global_load_lds DMA through a 2-pair double buffer,
// one __syncthreads per pair. ONLY the epilogue changed: bf16 partial
// stores to g_part are replaced by f32 global atomicAdd directly into out
// (prep pre-fills out with the bias; the 5 ks-blocks per output tile
// accumulate -- add order irrelevant). This deletes the reduce kernel (one
// dispatch + launch gap) and the 17.6MB+17.6MB+7.1MB g_part round-trip;
// out is 7MB -> atomics resolve in L2 (Guideline 12: device-scope by
// default). Accuracy improves: no bf16 rounding of partials.
__global__ __launch_bounds__(256, 2) void gemm_masked(float* __restrict__ out) {
  __shared__ __align__(16) unsigned char sB[AOFF + 16384];

  const int n = blockIdx.x;                  // 0..1079
  const int m = ((n & 7) * 135) + (n >> 3);  // XCD-contiguous work id
  const int ltile = m % 18;                  // l-tile of 128
  const int s  = m / 18;                     // slice 0..59 = (otile,bg,ks)
  const int otile = s % 3;
  const int zz = s / 3;                      // 0..19
  const int bg = zz & 3;
  const int ks = zz >> 2;                    // kernel row 0..4
  const int b  = bg >> 1;
  const int lbase = ltile * 128, obase = otile * 64;
  const int tid = threadIdx.x, lane = tid & 63, wv = tid >> 6;
  const int q = lane >> 4, m16 = lane & 15;

  // per-thread A source: granule tid (16B) of chunk t's 4KB otile slab
  const unsigned short* aslab =
      g_wa + ((size_t)bg * NCHUNK + ks * 30) * 6144 + otile * 2048 + tid * 8;

  // async 16B global->LDS; lds side = wave-uniform base + lane*16
#define GLL(gsrc, ldsoff)                                                     \
  __builtin_amdgcn_global_load_lds(                                           \
      (const __attribute__((address_space(1))) void*)(gsrc),                  \
      (__attribute__((address_space(3))) void*)(sB + (ldsoff)), 16, 0, 0);

  // ---- prologue: issue A pair 0 into buf 0 (chunks 0,1)
  GLL(aslab,        AOFF + 0 * 4096 + wv * 1024)
  GLL(aslab + 6144, AOFF + 1 * 4096 + wv * 1024)

  // ---- stage window rows [wl0, wl0+131] (contiguous in g_xt) into LDS
  const int wl0 = lbase + (ks - 2) * HWDIM - 2;
  const unsigned short* xwin = g_xt + XPAD + (ptrdiff_t)(b * LPIX + wl0) * CINCH;
  #pragma unroll
  for (int it = 0; it < 13; ++it) {          // 132*24 = 3168 granules of 16 B
    const int i = it * 256 + tid;
    if (it < 12 || i < 3168) {
      const int r = i / 24, g = i % 24;      // src is linear: granule i
      *reinterpret_cast<uint4*>(sB + r * LROW + g * 16) =
          *reinterpret_cast<const uint4*>(xwin + i * 8);
    }
  }
  if (tid < 4) {  // zero line
    uint4 z; z.x = z.y = z.z = z.w = 0u;
    *reinterpret_cast<uint4*>(sB + ZOFF + tid * 16) = z;
  }

  // ---- per-fragment masks (pre-shifted by ks*5) and LDS base offsets
  unsigned bls[2], bhs[2], bboff[2];
  #pragma unroll
  for (int jj = 0; jj < 2; ++jj) {
    const int lj = wv * 32 + jj * 16 + m16;
    const unsigned long long bits = g_m64[bg * LPIX + lbase + lj];
    bls[jj] = ((unsigned)(bits & 0x1ffffffull)) >> (ks * 5);
    bhs[jj] = ((unsigned)((bits >> KTAP) & 0x1ffffffull)) >> (ks * 5);
    bboff[jj] = lj * LROW + q * 16;
  }
  const unsigned zoff = ZOFF + q * 16;

#define LOADB(tt, Bf)                                                       \
  {                                                                         \
    const int _kt = (tt) / 6, _ci = (tt) % 6;                               \
    _Pragma("unroll")                                                       \
    for (int jj = 0; jj < 2; ++jj) {                                        \
      const unsigned bit = (((_ci >= 3) ? bhs[jj] : bls[jj]) >> _kt) & 1u;  \
      const unsigned off =                                                  \
          bit ? (bboff[jj] + _kt * LROW + _ci * 64) : zoff;                 \
      Bf[jj] = *reinterpret_cast<const short8*>(sB + off);                  \
    }                                                                       \
  }

  float4v acc[4][2];
  #pragma unroll
  for (int i = 0; i < 4; ++i)
    #pragma unroll
    for (int jj = 0; jj < 2; ++jj) acc[i][jj] = (float4v)(0.0f);

  __syncthreads();   // window + A pair 0 visible (vmcnt drained by barrier)

  #pragma unroll
  for (int pt = 0; pt < 15; ++pt) {
    // issue async A staging for pair pt+1 into the other buffer FIRST
    // (safe: that buffer's reads finished before the previous barrier)
    if (pt < 14) {
      const unsigned short* src = aslab + (size_t)(2 * pt + 2) * 6144;
      const int boff = AOFF + ((pt + 1) & 1) * 8192 + wv * 1024;
      GLL(src,        boff)
      GLL(src + 6144, boff + 4096)
    }
    // compute pair pt from A buffer (pt&1)
    #pragma unroll
    for (int cc = 0; cc < 2; ++cc) {
      const int tt = 2 * pt + cc;
      const unsigned char* ab = sB + AOFF + (pt & 1) * 8192 + cc * 4096;
      short8 Afr[4];
      #pragma unroll
      for (int i = 0; i < 4; ++i)
        Afr[i] = *reinterpret_cast<const short8*>(ab + i * 1024 + m16 * 64 + q * 16);
      short8 Bfr[2];
      LOADB(tt, Bfr)
      #pragma unroll
      for (int i = 0; i < 4; ++i)
        #pragma unroll
        for (int jj = 0; jj < 2; ++jj)
          acc[i][jj] = __builtin_amdgcn_mfma_f32_16x16x32_bf16(Afr[i], Bfr[jj],
                                                               acc[i][jj], 0, 0, 0);
    }
    // ONE barrier per pair: drains pair pt+1's DMA, publishes the buffer
    if (pt < 14) __syncthreads();
  }
#undef LOADB
#undef GLL

  // Epilogue: f32 atomic accumulate into out[bg*OG + o][l].
  // C/D layout: col = lane&15, row = q*4 + r.
  float* ob = out + (size_t)bg * OG * LPIX;
  #pragma unroll
  for (int i = 0; i < 4; ++i) {
    const int og = obase + i * 16 + q * 4;
    #pragma unroll
    for (int jj = 0; jj < 2; ++jj) {
      const int cl = lbase + wv * 32 + jj * 16 + m16;
      #pragma unroll
      for (int r = 0; r < 4; ++r)
        atomicAdd(&ob[(size_t)(og + r) * LPIX + cl], acc[i][jj][r]);
    }
  }
}

// ---------------------------------------------------------------------------
extern "C" void kernel_launch(void* const* d_in, const int* in_sizes, int n_in,
                              void* d_out, int out_size, void* d_ws, size_t ws_size,
                              hipStream_t stream) {
  const float* x   = (const float*)d_in[0];
  const int*   tg  = (const int*)d_in[1];
  const float* dkw = (const float*)d_in[2];
  const float* dkb = (const float*)d_in[3];
  float* out = (float*)d_out;

  prep<<<dim3(2928), 256, 0, stream>>>(x, tg, dkw, dkb, out);
  gemm_masked<<<dim3(1080), 256, 0, stream>>>(out);
}

// Round 10
// 118.085 us; speedup vs baseline: 1.0134x; 1.0134x over previous
//
#include <hip/hip_runtime.h>
#include <hip/hip_bf16.h>

// Problem constants
#define BATCH 2
#define GRP   2
#define NBG   4            // BATCH*GRP
#define CINCH 192          // input channels
#define OG    192          // output channels per group
#define HWDIM 48
#define LPIX  2304         // 48*48
#define KTAP  25           // 5x5
#define IDIM  4800         // CINCH*KTAP
#define NCHUNK 150         // IDIM/32
#define NSLICE 6           // K-split: rows 0,1,3,4 whole; row 2 split kt{0-2}/{3,4}
#define XPAD  24576        // 128 l-rows * 192 c of padding each side of g_xt
#define OUTEL (NBG * OG * LPIX)   // 1769472
#define LROW  400          // LDS bytes per staged B row (384 data + 16 pad)
#define ZOFF  (132 * LROW) // zero line offset (52800)
#define AOFF  (ZOFF + 64)  // A double-buffer offset; LDS total = AOFF + 16384

typedef __attribute__((ext_vector_type(4))) float  float4v;
typedef __attribute__((ext_vector_type(8))) short  short8;

// Static device scratch
// A, fragment-major: [bg][t][ot(3)][i(4)][m(16)][q(4)][e(8)] bf16
__device__ __align__(16) unsigned short g_wa[(size_t)NBG * NCHUNK * 6144];
__device__ __align__(16) unsigned short g_xt[XPAD + BATCH * LPIX * CINCH + XPAD]; // [b][l][c] bf16, padded
__device__ unsigned long long g_m64[NBG * LPIX];   // 50 mask bits per (bg,l)
__device__ __align__(16) unsigned short g_part[(size_t)NSLICE * OUTEL];  // bf16 K-split partials

__device__ __forceinline__ unsigned short f2bf(float f) {
  union { float f; unsigned int u; } un; un.f = f;
  unsigned int u = un.u;
  return (unsigned short)((u + 0x7fffu + ((u >> 16) & 1u)) >> 16);  // RNE
}

// ---------------------------------------------------------------------------
// ONE prep dispatch, block ranges:
//  [0,216)      transpose+cvt x -> g_xt
//  [216,984)    reorder dkw -> g_wa (fragment-major, coalesced 64B stores)
//  [984,1176)   mask bits -> g_m64
//  [1176,1200)  zero g_xt pads
__global__ __launch_bounds__(256) void prep(
    const float* __restrict__ x, const int* __restrict__ tg,
    const float* __restrict__ dkw) {
  __shared__ __align__(16) unsigned char smem[19200];
  const int bx = blockIdx.x, tid = threadIdx.x;

  if (bx < 216) {  // ---- transpose: 64c x 64l tiles via LDS (stride 68)
    unsigned short* tile = (unsigned short*)smem;
    const int c0 = (bx % 3) * 64;
    const int l0 = ((bx / 3) % 36) * 64;
    const int b  = bx / 108;
    #pragma unroll
    for (int it = 0; it < 4; ++it) {
      const int idx = it * 256 + tid;
      const int cl = idx >> 4, lq = idx & 15;
      const float4 v = reinterpret_cast<const float4*>(
          x + ((size_t)b * CINCH + c0 + cl) * LPIX + l0)[lq];
      unsigned short* tp = &tile[cl * 68 + lq * 4];
      tp[0] = f2bf(v.x); tp[1] = f2bf(v.y); tp[2] = f2bf(v.z); tp[3] = f2bf(v.w);
    }
    __syncthreads();
    unsigned short* dst = g_xt + XPAD + ((size_t)b * LPIX) * CINCH;
    #pragma unroll
    for (int it = 0; it < 2; ++it) {
      const int idx = it * 256 + tid;
      const int c8 = idx & 7, ll = idx >> 3;
      unsigned short pk[8];
      #pragma unroll
      for (int e = 0; e < 8; ++e) pk[e] = tile[(c8 * 8 + e) * 68 + ll];
      *reinterpret_cast<uint4*>(dst + (size_t)(l0 + ll) * CINCH + c0 + c8 * 8) =
          *reinterpret_cast<const uint4*>(pk);
    }
  } else if (bx < 984) {  // ---- weight reorder, fragment-major
    float* row = (float*)smem;                 // 4800 floats
    const int blk = bx - 216;                  // bg*192 + o
    const int bg = blk / OG, o = blk % OG;
    const float* src = dkw + (size_t)blk * IDIM;
    for (int i = tid; i < IDIM / 4; i += 256)
      reinterpret_cast<float4*>(row)[i] = reinterpret_cast<const float4*>(src)[i];
    __syncthreads();
    const int ot = o >> 6, fi = (o >> 4) & 3, m = o & 15;
    unsigned short* wbase =
        g_wa + (size_t)bg * NCHUNK * 6144 + ot * 2048 + fi * 512 + m * 32;
    for (int t = tid; t < NCHUNK; t += 256) {  // one 64B granule per t
      const int kk = t / 6, c0 = (t % 6) * 32;
      unsigned int pk[16];
      #pragma unroll
      for (int q = 0; q < 4; ++q)
        #pragma unroll
        for (int e = 0; e < 4; ++e) {
          const int c = c0 + q * 8 + e * 2;
          const unsigned lo = f2bf(row[c * KTAP + kk]);
          const unsigned hi = f2bf(row[(c + 1) * KTAP + kk]);
          pk[q * 4 + e] = lo | (hi << 16);
        }
      unsigned short* dst = wbase + (size_t)t * 6144;
      #pragma unroll
      for (int q = 0; q < 4; ++q)
        reinterpret_cast<uint4*>(dst)[q] = *reinterpret_cast<const uint4*>(pk + q * 4);
    }
  } else if (bx < 1176) {  // ---- mask bits
    const int blk = bx - 984;                  // bg*48 + h
    const int bg = blk / HWDIM, h = blk % HWDIM;
    const int b = bg >> 1, g = bg & 1;
    int* tgs = (int*)smem;                     // [2][5][48]
    for (int i = tid; i < 480; i += 256) {
      const int g2 = i / 240, r5 = (i / 48) % 5, w = i % 48;
      const int hh = h + r5 - 2;
      tgs[i] = (hh >= 0 && hh < HWDIM)
                   ? tg[((b * GRP + g2) * HWDIM + hh) * HWDIM + w]
                   : 0x7fffffff;
    }
    __syncthreads();
    if (tid < HWDIM) {
      const int w = tid;
      const int center = tgs[g * 240 + 96 + w];
      unsigned long long bits = 0ull;
      #pragma unroll
      for (int g2 = 0; g2 < GRP; ++g2)
        #pragma unroll
        for (int kk = 0; kk < KTAP; ++kk) {
          const int ww = w + kk % 5 - 2;
          if (ww >= 0 && ww < HWDIM && tgs[g2 * 240 + (kk / 5) * 48 + ww] < center)
            bits |= 1ull << (g2 * KTAP + kk);
        }
      g_m64[bg * LPIX + h * HWDIM + w] = bits;
    }
  } else {  // ---- zero g_xt pads (2 x 48 KiB)
    const int idx = (bx - 1176) * 256 + tid;   // 0..6143, 16B each
    uint4 z; z.x = z.y = z.z = z.w = 0u;
    if (idx < 3072)
      reinterpret_cast<uint4*>(g_xt)[idx] = z;
    else
      reinterpret_cast<uint4*>(g_xt + XPAD + (size_t)BATCH * LPIX * CINCH)[idx - 3072] = z;
  }
}

// ---------------------------------------------------------------------------
// GEMM (R21): R17 body verbatim (best measured: 107.5us total; 256 threads,
// o64 x l128 tile, B window + zero line in LDS, A staged by 16B
// global_load_lds DMA, 2-pair double buffer, one __syncthreads per pair).
// ONE change: the K-split goes 5 -> 6 slices by splitting kernel row ks=2
// into pairs [0,9) (kt 0..2, 18 chunks) and [9,15) (kt 3,4, 12 chunks).
// Rationale: 1080 equal blocks on 512 co-residency slots (2 blocks/CU) =
// 2.11 rounds -> greedy makespan ~3 block-durations, ~30% idle tail (~8us).
// R18/R19 throughput changes were flat -> tail-bound, not pipe-bound.
// 1296 mixed-length blocks pack the slots better (expected ~2.3-2.5
// rounds-equivalent). Loop bounds become runtime [p0,p1); body unchanged.
__global__ __launch_bounds__(256, 2) void gemm_masked() {
  __shared__ __align__(16) unsigned char sB[AOFF + 16384];

  const int n = blockIdx.x;                  // 0..1295
  const int m = ((n & 7) * 162) + (n >> 3);  // XCD-contiguous work id (1296=8*162)
  const int ltile = m % 18;                  // l-tile of 128
  const int s  = m / 18;                     // 0..71 = (otile, bg, slice)
  const int otile = s % 3;
  const int zz = s / 3;                      // 0..23
  const int bg = zz & 3;
  const int slice = zz >> 2;                 // 0..5
  // slice -> (kernel row ks, pair range [p0,p1))
  const int ks = (slice < 2) ? slice : ((slice < 4) ? 2 : slice - 1);
  const int p0 = (slice == 3) ? 9 : 0;
  const int p1 = (slice == 2) ? 9 : 15;
  const int b  = bg >> 1;
  const int lbase = ltile * 128, obase = otile * 64;
  const int tid = threadIdx.x, lane = tid & 63, wv = tid >> 6;
  const int q = lane >> 4, m16 = lane & 15;

  // per-thread A source: granule tid (16B) of chunk t's 4KB otile slab
  const unsigned short* aslab =
      g_wa + ((size_t)bg * NCHUNK + ks * 30) * 6144 + otile * 2048 + tid * 8;

  // async 16B global->LDS; lds side = wave-uniform base + lane*16
#define GLL(gsrc, ldsoff)                                                     \
  __builtin_amdgcn_global_load_lds(                                           \
      (const __attribute__((address_space(1))) void*)(gsrc),                  \
      (__attribute__((address_space(3))) void*)(sB + (ldsoff)), 16, 0, 0);

  // ---- prologue: issue A pair p0 into buf (p0&1) (chunks 2p0, 2p0+1)
  {
    const unsigned short* src = aslab + (size_t)(2 * p0) * 6144;
    const int boff = AOFF + (p0 & 1) * 8192 + wv * 1024;
    GLL(src,        boff)
    GLL(src + 6144, boff + 4096)
  }

  // ---- stage window rows [wl0, wl0+131] (contiguous in g_xt) into LDS
  const int wl0 = lbase + (ks - 2) * HWDIM - 2;
  const unsigned short* xwin = g_xt + XPAD + (ptrdiff_t)(b * LPIX + wl0) * CINCH;
  #pragma unroll
  for (int it = 0; it < 13; ++it) {          // 132*24 = 3168 granules of 16 B
    const int i = it * 256 + tid;
    if (it < 12 || i < 3168) {
      const int r = i / 24, g = i % 24;      // src is linear: granule i
      *reinterpret_cast<uint4*>(sB + r * LROW + g * 16) =
          *reinterpret_cast<const uint4*>(xwin + i * 8);
    }
  }
  if (tid < 4) {  // zero line
    uint4 z; z.x = z.y = z.z = z.w = 0u;
    *reinterpret_cast<uint4*>(sB + ZOFF + tid * 16) = z;
  }

  // ---- per-fragment masks (pre-shifted by ks*5) and LDS base offsets
  unsigned bls[2], bhs[2], bboff[2];
  #pragma unroll
  for (int jj = 0; jj < 2; ++jj) {
    const int lj = wv * 32 + jj * 16 + m16;
    const unsigned long long bits = g_m64[bg * LPIX + lbase + lj];
    bls[jj] = ((unsigned)(bits & 0x1ffffffull)) >> (ks * 5);
    bhs[jj] = ((unsigned)((bits >> KTAP) & 0x1ffffffull)) >> (ks * 5);
    bboff[jj] = lj * LROW + q * 16;
  }
  const unsigned zoff = ZOFF + q * 16;

#define LOADB(tt, Bf)                                                       \
  {                                                                         \
    const int _kt = (tt) / 6, _ci = (tt) % 6;                               \
    _Pragma("unroll")                                                       \
    for (int jj = 0; jj < 2; ++jj) {                                        \
      const unsigned bit = (((_ci >= 3) ? bhs[jj] : bls[jj]) >> _kt) & 1u;  \
      const unsigned off =                                                  \
          bit ? (bboff[jj] + _kt * LROW + _ci * 64) : zoff;                 \
      Bf[jj] = *reinterpret_cast<const short8*>(sB + off);                  \
    }                                                                       \
  }

  float4v acc[4][2];
  #pragma unroll
  for (int i = 0; i < 4; ++i)
    #pragma unroll
    for (int jj = 0; jj < 2; ++jj) acc[i][jj] = (float4v)(0.0f);

  __syncthreads();   // window + A pair p0 visible (vmcnt drained by barrier)

  for (int pt = p0; pt < p1; ++pt) {
    // issue async A staging for pair pt+1 into the other buffer FIRST
    // (safe: that buffer's reads finished before the previous barrier)
    if (pt + 1 < p1) {
      const unsigned short* src = aslab + (size_t)(2 * pt + 2) * 6144;
      const int boff = AOFF + ((pt + 1) & 1) * 8192 + wv * 1024;
      GLL(src,        boff)
      GLL(src + 6144, boff + 4096)
    }
    // compute pair pt from A buffer (pt&1)
    #pragma unroll
    for (int cc = 0; cc < 2; ++cc) {
      const int tt = 2 * pt + cc;
      const unsigned char* ab = sB + AOFF + (pt & 1) * 8192 + cc * 4096;
      short8 Afr[4];
      #pragma unroll
      for (int i = 0; i < 4; ++i)
        Afr[i] = *reinterpret_cast<const short8*>(ab + i * 1024 + m16 * 64 + q * 16);
      short8 Bfr[2];
      LOADB(tt, Bfr)
      #pragma unroll
      for (int i = 0; i < 4; ++i)
        #pragma unroll
        for (int jj = 0; jj < 2; ++jj)
          acc[i][jj] = __builtin_amdgcn_mfma_f32_16x16x32_bf16(Afr[i], Bfr[jj],
                                                               acc[i][jj], 0, 0, 0);
    }
    // ONE barrier per pair: drains pair pt+1's DMA, publishes the buffer
    if (pt + 1 < p1) __syncthreads();
  }
#undef LOADB
#undef GLL

  // Epilogue: bf16 partial stores to g_part[slice][bg][o][l].
  // C/D layout: col = lane&15, row = q*4 + r.
  unsigned short* pb = g_part + (size_t)slice * OUTEL + (size_t)bg * OG * LPIX;
  #pragma unroll
  for (int i = 0; i < 4; ++i) {
    const int og = obase + i * 16 + q * 4;
    #pragma unroll
    for (int jj = 0; jj < 2; ++jj) {
      const int cl = lbase + wv * 32 + jj * 16 + m16;
      #pragma unroll
      for (int r = 0; r < 4; ++r)
        pb[(size_t)(og + r) * LPIX + cl] = f2bf(acc[i][jj][r]);
    }
  }
}

// ---------------------------------------------------------------------------
// Reduce: out = sum_slice bf16(g_part[slice]) + bias. 8 elements per thread.
__global__ __launch_bounds__(256) void reduce_part(
    const float* __restrict__ dkb, float* __restrict__ out) {
  const int t8 = blockIdx.x * 256 + threadIdx.x;   // 0..221183
  const size_t e0 = (size_t)t8 * 8;
  const int row = (int)(e0 / LPIX);                // bg*192 + o (8 els same row)
  const float bias = dkb[row];
  float s[8];
  #pragma unroll
  for (int k = 0; k < 8; ++k) s[k] = bias;
  #pragma unroll
  for (int ks = 0; ks < NSLICE; ++ks) {
    const uint4 v = *reinterpret_cast<const uint4*>(
        g_part + (size_t)ks * OUTEL + e0);
    const unsigned u[4] = {v.x, v.y, v.z, v.w};
    #pragma unroll
    for (int p = 0; p < 4; ++p) {
      union { unsigned u; float f; } lo, hi;
      lo.u = u[p] << 16;
      hi.u = u[p] & 0xffff0000u;
      s[2 * p]     += lo.f;
      s[2 * p + 1] += hi.f;
    }
  }
  float4 o0, o1;
  o0.x = s[0]; o0.y = s[1]; o0.z = s[2]; o0.w = s[3];
  o1.x = s[4]; o1.y = s[5]; o1.z = s[6]; o1.w = s[7];
  reinterpret_cast<float4*>(out)[t8 * 2]     = o0;
  reinterpret_cast<float4*>(out)[t8 * 2 + 1] = o1;
}

// ---------------------------------------------------------------------------
extern "C" void kernel_launch(void* const* d_in, const int* in_sizes, int n_in,
                              void* d_out, int out_size, void* d_ws, size_t ws_size,
                              hipStream_t stream) {
  const float* x   = (const float*)d_in[0];
  const int*   tg  = (const int*)d_in[1];
  const float* dkw = (const float*)d_in[2];
  const float* dkb = (const float*)d_in[3];
  float* out = (float*)d_out;

  prep<<<dim3(1200), 256, 0, stream>>>(x, tg, dkw);
  gemm_masked<<<dim3(1296), 256, 0, stream>>>();
  reduce_part<<<dim3(OUTEL / 2048), 256, 0, stream>>>(dkb, out);
}

// Round 11
// 107.978 us; speedup vs baseline: 1.1083x; 1.0936x over previous
//
#include <hip/hip_runtime.h>
#include <hip/hip_bf16.h>

// Problem constants
#define BATCH 2
#define GRP   2
#define NBG   4            // BATCH*GRP
#define CINCH 192          // input channels
#define OG    192          // output channels per group
#define HWDIM 48
#define LPIX  2304         // 48*48
#define KTAP  25           // 5x5
#define IDIM  4800         // CINCH*KTAP
#define NCHUNK 150         // IDIM/32
#define KSPLIT 5           // one kernel row (5 taps) per split
#define XPAD  24576        // 128 l-rows * 192 c of padding each side of g_xt
#define OUTEL (NBG * OG * LPIX)   // 1769472
#define LROW  400          // LDS bytes per staged B row (384 data + 16 pad)
#define ZOFF  (132 * LROW) // zero region offset (52800)
#define AOFF  (ZOFF + 1024) // A double-buffer offset; LDS total = AOFF + 16384

typedef __attribute__((ext_vector_type(4))) float  float4v;
typedef __attribute__((ext_vector_type(8))) short  short8;

// Static device scratch
// A, fragment-major: [bg][t][ot(3)][i(4)][m(16)][q(4)][e(8)] bf16
__device__ __align__(16) unsigned short g_wa[(size_t)NBG * NCHUNK * 6144];
__device__ __align__(16) unsigned short g_xt[XPAD + BATCH * LPIX * CINCH + XPAD]; // [b][l][c] bf16, padded
__device__ unsigned long long g_m64[NBG * LPIX];   // 50 mask bits per (bg,l)
__device__ __align__(16) unsigned short g_part[(size_t)KSPLIT * OUTEL];  // bf16 K-split partials

__device__ __forceinline__ unsigned short f2bf(float f) {
  union { float f; unsigned int u; } un; un.f = f;
  unsigned int u = un.u;
  return (unsigned short)((u + 0x7fffu + ((u >> 16) & 1u)) >> 16);  // RNE
}

// ---------------------------------------------------------------------------
// ONE prep dispatch, block ranges:
//  [0,216)      transpose+cvt x -> g_xt
//  [216,984)    reorder dkw -> g_wa (fragment-major, coalesced 64B stores)
//  [984,1176)   mask bits -> g_m64
//  [1176,1200)  zero g_xt pads
__global__ __launch_bounds__(256) void prep(
    const float* __restrict__ x, const int* __restrict__ tg,
    const float* __restrict__ dkw) {
  __shared__ __align__(16) unsigned char smem[19200];
  const int bx = blockIdx.x, tid = threadIdx.x;

  if (bx < 216) {  // ---- transpose: 64c x 64l tiles via LDS (stride 68)
    unsigned short* tile = (unsigned short*)smem;
    const int c0 = (bx % 3) * 64;
    const int l0 = ((bx / 3) % 36) * 64;
    const int b  = bx / 108;
    #pragma unroll
    for (int it = 0; it < 4; ++it) {
      const int idx = it * 256 + tid;
      const int cl = idx >> 4, lq = idx & 15;
      const float4 v = reinterpret_cast<const float4*>(
          x + ((size_t)b * CINCH + c0 + cl) * LPIX + l0)[lq];
      unsigned short* tp = &tile[cl * 68 + lq * 4];
      tp[0] = f2bf(v.x); tp[1] = f2bf(v.y); tp[2] = f2bf(v.z); tp[3] = f2bf(v.w);
    }
    __syncthreads();
    unsigned short* dst = g_xt + XPAD + ((size_t)b * LPIX) * CINCH;
    #pragma unroll
    for (int it = 0; it < 2; ++it) {
      const int idx = it * 256 + tid;
      const int c8 = idx & 7, ll = idx >> 3;
      unsigned short pk[8];
      #pragma unroll
      for (int e = 0; e < 8; ++e) pk[e] = tile[(c8 * 8 + e) * 68 + ll];
      *reinterpret_cast<uint4*>(dst + (size_t)(l0 + ll) * CINCH + c0 + c8 * 8) =
          *reinterpret_cast<const uint4*>(pk);
    }
  } else if (bx < 984) {  // ---- weight reorder, fragment-major
    float* row = (float*)smem;                 // 4800 floats
    const int blk = bx - 216;                  // bg*192 + o
    const int bg = blk / OG, o = blk % OG;
    const float* src = dkw + (size_t)blk * IDIM;
    for (int i = tid; i < IDIM / 4; i += 256)
      reinterpret_cast<float4*>(row)[i] = reinterpret_cast<const float4*>(src)[i];
    __syncthreads();
    const int ot = o >> 6, fi = (o >> 4) & 3, m = o & 15;
    unsigned short* wbase =
        g_wa + (size_t)bg * NCHUNK * 6144 + ot * 2048 + fi * 512 + m * 32;
    for (int t = tid; t < NCHUNK; t += 256) {  // one 64B granule per t
      const int kk = t / 6, c0 = (t % 6) * 32;
      unsigned int pk[16];
      #pragma unroll
      for (int q = 0; q < 4; ++q)
        #pragma unroll
        for (int e = 0; e < 4; ++e) {
          const int c = c0 + q * 8 + e * 2;
          const unsigned lo = f2bf(row[c * KTAP + kk]);
          const unsigned hi = f2bf(row[(c + 1) * KTAP + kk]);
          pk[q * 4 + e] = lo | (hi << 16);
        }
      unsigned short* dst = wbase + (size_t)t * 6144;
      #pragma unroll
      for (int q = 0; q < 4; ++q)
        reinterpret_cast<uint4*>(dst)[q] = *reinterpret_cast<const uint4*>(pk + q * 4);
    }
  } else if (bx < 1176) {  // ---- mask bits
    const int blk = bx - 984;                  // bg*48 + h
    const int bg = blk / HWDIM, h = blk % HWDIM;
    const int b = bg >> 1, g = bg & 1;
    int* tgs = (int*)smem;                     // [2][5][48]
    for (int i = tid; i < 480; i += 256) {
      const int g2 = i / 240, r5 = (i / 48) % 5, w = i % 48;
      const int hh = h + r5 - 2;
      tgs[i] = (hh >= 0 && hh < HWDIM)
                   ? tg[((b * GRP + g2) * HWDIM + hh) * HWDIM + w]
                   : 0x7fffffff;
    }
    __syncthreads();
    if (tid < HWDIM) {
      const int w = tid;
      const int center = tgs[g * 240 + 96 + w];
      unsigned long long bits = 0ull;
      #pragma unroll
      for (int g2 = 0; g2 < GRP; ++g2)
        #pragma unroll
        for (int kk = 0; kk < KTAP; ++kk) {
          const int ww = w + kk % 5 - 2;
          if (ww >= 0 && ww < HWDIM && tgs[g2 * 240 + (kk / 5) * 48 + ww] < center)
            bits |= 1ull << (g2 * KTAP + kk);
        }
      g_m64[bg * LPIX + h * HWDIM + w] = bits;
    }
  } else {  // ---- zero g_xt pads (2 x 48 KiB)
    const int idx = (bx - 1176) * 256 + tid;   // 0..6143, 16B each
    uint4 z; z.x = z.y = z.z = z.w = 0u;
    if (idx < 3072)
      reinterpret_cast<uint4*>(g_xt)[idx] = z;
    else
      reinterpret_cast<uint4*>(g_xt + XPAD + (size_t)BATCH * LPIX * CINCH)[idx - 3072] = z;
  }
}

// ---------------------------------------------------------------------------
// GEMM (R22): R17 body verbatim (best measured: 107.5us total) with ONE
// fix: the masked-tap redirect target grows from a single shared 64B zero
// line to a 1KB zero REGION addressed as ZOFF + m16*64 + q*16. R20's
// profile of this body showed SQ_LDS_BANK_CONFLICT = 3.0M/dispatch; A-reads
// and unmasked B-reads are provably uniform across banks (A: addresses
// 16*(4*m16+q) tile 1024B exactly; B: LROW=400 -> each bank 8x4B), so the
// conflicts come from ~63%-masked rows piling all their q-lanes onto the
// SAME 64B line (banks 16..31 only). Lane-dependent zero addresses restore
// the uniform 32-bank tiling for masked lanes. Costs 960B LDS (70.2KB
// total, still 2 blocks/CU); zero-fill is tid<64. R21's runtime-bound loop
// regression (118us) is reverted: bounds are compile-time, fully unrolled.
__global__ __launch_bounds__(256, 2) void gemm_masked() {
  __shared__ __align__(16) unsigned char sB[AOFF + 16384];

  const int n = blockIdx.x;                  // 0..1079
  const int m = ((n & 7) * 135) + (n >> 3);  // XCD-contiguous work id
  const int ltile = m % 18;                  // l-tile of 128
  const int s  = m / 18;                     // slice 0..59 = (otile,bg,ks)
  const int otile = s % 3;
  const int zz = s / 3;                      // 0..19
  const int bg = zz & 3;
  const int ks = zz >> 2;                    // kernel row 0..4
  const int b  = bg >> 1;
  const int lbase = ltile * 128, obase = otile * 64;
  const int tid = threadIdx.x, lane = tid & 63, wv = tid >> 6;
  const int q = lane >> 4, m16 = lane & 15;

  // per-thread A source: granule tid (16B) of chunk t's 4KB otile slab
  const unsigned short* aslab =
      g_wa + ((size_t)bg * NCHUNK + ks * 30) * 6144 + otile * 2048 + tid * 8;

  // async 16B global->LDS; lds side = wave-uniform base + lane*16
#define GLL(gsrc, ldsoff)                                                     \
  __builtin_amdgcn_global_load_lds(                                           \
      (const __attribute__((address_space(1))) void*)(gsrc),                  \
      (__attribute__((address_space(3))) void*)(sB + (ldsoff)), 16, 0, 0);

  // ---- prologue: issue A pair 0 into buf 0 (chunks 0,1)
  GLL(aslab,        AOFF + 0 * 4096 + wv * 1024)
  GLL(aslab + 6144, AOFF + 1 * 4096 + wv * 1024)

  // ---- stage window rows [wl0, wl0+131] (contiguous in g_xt) into LDS
  const int wl0 = lbase + (ks - 2) * HWDIM - 2;
  const unsigned short* xwin = g_xt + XPAD + (ptrdiff_t)(b * LPIX + wl0) * CINCH;
  #pragma unroll
  for (int it = 0; it < 13; ++it) {          // 132*24 = 3168 granules of 16 B
    const int i = it * 256 + tid;
    if (it < 12 || i < 3168) {
      const int r = i / 24, g = i % 24;      // src is linear: granule i
      *reinterpret_cast<uint4*>(sB + r * LROW + g * 16) =
          *reinterpret_cast<const uint4*>(xwin + i * 8);
    }
  }
  if (tid < 64) {  // zero region: 1 KB, tiles all 32 banks
    uint4 z; z.x = z.y = z.z = z.w = 0u;
    *reinterpret_cast<uint4*>(sB + ZOFF + tid * 16) = z;
  }

  // ---- per-fragment masks (pre-shifted by ks*5) and LDS base offsets
  unsigned bls[2], bhs[2], bboff[2];
  #pragma unroll
  for (int jj = 0; jj < 2; ++jj) {
    const int lj = wv * 32 + jj * 16 + m16;
    const unsigned long long bits = g_m64[bg * LPIX + lbase + lj];
    bls[jj] = ((unsigned)(bits & 0x1ffffffull)) >> (ks * 5);
    bhs[jj] = ((unsigned)((bits >> KTAP) & 0x1ffffffull)) >> (ks * 5);
    bboff[jj] = lj * LROW + q * 16;
  }
  const unsigned zoff = ZOFF + m16 * 64 + q * 16;   // lane-spread zero read

#define LOADB(tt, Bf)                                                       \
  {                                                                         \
    const int _kt = (tt) / 6, _ci = (tt) % 6;                               \
    _Pragma("unroll")                                                       \
    for (int jj = 0; jj < 2; ++jj) {                                        \
      const unsigned bit = (((_ci >= 3) ? bhs[jj] : bls[jj]) >> _kt) & 1u;  \
      const unsigned off =                                                  \
          bit ? (bboff[jj] + _kt * LROW + _ci * 64) : zoff;                 \
      Bf[jj] = *reinterpret_cast<const short8*>(sB + off);                  \
    }                                                                       \
  }

  float4v acc[4][2];
  #pragma unroll
  for (int i = 0; i < 4; ++i)
    #pragma unroll
    for (int jj = 0; jj < 2; ++jj) acc[i][jj] = (float4v)(0.0f);

  __syncthreads();   // window + A pair 0 visible (vmcnt drained by barrier)

  #pragma unroll
  for (int pt = 0; pt < 15; ++pt) {
    // issue async A staging for pair pt+1 into the other buffer FIRST
    // (safe: that buffer's reads finished before the previous barrier)
    if (pt < 14) {
      const unsigned short* src = aslab + (size_t)(2 * pt + 2) * 6144;
      const int boff = AOFF + ((pt + 1) & 1) * 8192 + wv * 1024;
      GLL(src,        boff)
      GLL(src + 6144, boff + 4096)
    }
    // compute pair pt from A buffer (pt&1)
    #pragma unroll
    for (int cc = 0; cc < 2; ++cc) {
      const int tt = 2 * pt + cc;
      const unsigned char* ab = sB + AOFF + (pt & 1) * 8192 + cc * 4096;
      short8 Afr[4];
      #pragma unroll
      for (int i = 0; i < 4; ++i)
        Afr[i] = *reinterpret_cast<const short8*>(ab + i * 1024 + m16 * 64 + q * 16);
      short8 Bfr[2];
      LOADB(tt, Bfr)
      #pragma unroll
      for (int i = 0; i < 4; ++i)
        #pragma unroll
        for (int jj = 0; jj < 2; ++jj)
          acc[i][jj] = __builtin_amdgcn_mfma_f32_16x16x32_bf16(Afr[i], Bfr[jj],
                                                               acc[i][jj], 0, 0, 0);
    }
    // ONE barrier per pair: drains pair pt+1's DMA, publishes the buffer
    if (pt < 14) __syncthreads();
  }
#undef LOADB
#undef GLL

  // Epilogue: bf16 partial stores to g_part[ks][bg][o][l].
  // C/D layout: col = lane&15, row = q*4 + r.
  unsigned short* pb = g_part + (size_t)ks * OUTEL + (size_t)bg * OG * LPIX;
  #pragma unroll
  for (int i = 0; i < 4; ++i) {
    const int og = obase + i * 16 + q * 4;
    #pragma unroll
    for (int jj = 0; jj < 2; ++jj) {
      const int cl = lbase + wv * 32 + jj * 16 + m16;
      #pragma unroll
      for (int r = 0; r < 4; ++r)
        pb[(size_t)(og + r) * LPIX + cl] = f2bf(acc[i][jj][r]);
    }
  }
}

// ---------------------------------------------------------------------------
// Reduce: out = sum_ks bf16(g_part[ks]) + bias. 8 elements per thread.
__global__ __launch_bounds__(256) void reduce_part(
    const float* __restrict__ dkb, float* __restrict__ out) {
  const int t8 = blockIdx.x * 256 + threadIdx.x;   // 0..221183
  const size_t e0 = (size_t)t8 * 8;
  const int row = (int)(e0 / LPIX);                // bg*192 + o (8 els same row)
  const float bias = dkb[row];
  float s[8];
  #pragma unroll
  for (int k = 0; k < 8; ++k) s[k] = bias;
  #pragma unroll
  for (int ks = 0; ks < KSPLIT; ++ks) {
    const uint4 v = *reinterpret_cast<const uint4*>(
        g_part + (size_t)ks * OUTEL + e0);
    const unsigned u[4] = {v.x, v.y, v.z, v.w};
    #pragma unroll
    for (int p = 0; p < 4; ++p) {
      union { unsigned u; float f; } lo, hi;
      lo.u = u[p] << 16;
      hi.u = u[p] & 0xffff0000u;
      s[2 * p]     += lo.f;
      s[2 * p + 1] += hi.f;
    }
  }
  float4 o0, o1;
  o0.x = s[0]; o0.y = s[1]; o0.z = s[2]; o0.w = s[3];
  o1.x = s[4]; o1.y = s[5]; o1.z = s[6]; o1.w = s[7];
  reinterpret_cast<float4*>(out)[t8 * 2]     = o0;
  reinterpret_cast<float4*>(out)[t8 * 2 + 1] = o1;
}

// ---------------------------------------------------------------------------
extern "C" void kernel_launch(void* const* d_in, const int* in_sizes, int n_in,
                              void* d_out, int out_size, void* d_ws, size_t ws_size,
                              hipStream_t stream) {
  const float* x   = (const float*)d_in[0];
  const int*   tg  = (const int*)d_in[1];
  const float* dkw = (const float*)d_in[2];
  const float* dkb = (const float*)d_in[3];
  float* out = (float*)d_out;

  prep<<<dim3(1200), 256, 0, stream>>>(x, tg, dkw);
  gemm_masked<<<dim3(1080), 256, 0, stream>>>();
  reduce_part<<<dim3(OUTEL / 2048), 256, 0, stream>>>(dkb, out);
}